// Round 12
// baseline (1886.654 us; speedup 1.0000x reference)
//
#include <hip/hip_runtime.h>
#include <hip/hip_bf16.h>
#include <math.h>

#define L_ 4
#define B_ 64
#define N_ 511
#define D_ 256
#define H_ 8
#define DFF_ 512
#define S_ 512
#define HD_ 32
#define BW_ 7
#define BS_ (B_*S_)   // 32768 rows

typedef __attribute__((ext_vector_type(8))) short short8;   // 8 x bf16 bits
typedef __attribute__((ext_vector_type(4))) short short4v;  // 4 x bf16 bits
typedef __attribute__((ext_vector_type(4))) float f32x4;

#define L2E 1.44269504088896340f
#define QSCL (0.17677669529663687f * 1.44269504088896340f)   // rscale * log2(e)

// Device pass: resolve the 16x16x16 bf16 MFMA spelling. Host pass: stub.
#if defined(__HIP_DEVICE_COMPILE__)
#if __has_builtin(__builtin_amdgcn_mfma_f32_16x16x16bf16_1k)
#define MFMA16(p, v, c) __builtin_amdgcn_mfma_f32_16x16x16bf16_1k(p, v, c, 0, 0, 0)
#elif __has_builtin(__builtin_amdgcn_mfma_f32_16x16x16_bf16)
#define MFMA16(p, v, c) __builtin_amdgcn_mfma_f32_16x16x16_bf16(p, v, c, 0, 0, 0)
#else
#define MFMA16(p, v, c) (c)   /* unreachable on gfx950 per R4 evidence */
#endif
#else
#define MFMA16(p, v, c) (c)   /* host pass: never executed */
#endif

#if defined(__HIP_DEVICE_COMPILE__) && __has_builtin(__builtin_amdgcn_exp2f)
#define EXP2(x) __builtin_amdgcn_exp2f(x)
#else
#define EXP2(x) exp2f(x)
#endif

__device__ inline ushort f2b(float f) {
    unsigned u = __float_as_uint(f);
    unsigned r = (u + 0x7fffu + ((u >> 16) & 1u)) >> 16;   // RNE
    return (ushort)r;
}

// packed f32x2 -> bf16x2 in one uint (low = a); HW op on gfx950, SW fallback
#if defined(__HIP_DEVICE_COMPILE__) && __has_builtin(__builtin_amdgcn_cvt_pk_bf16_f32)
typedef __attribute__((ext_vector_type(2))) __bf16 bf16x2_t;
__device__ inline uint pk_bf16(float a, float b) {
    bf16x2_t r = __builtin_amdgcn_cvt_pk_bf16_f32(a, b);
    return *(uint*)&r;
}
#else
__device__ inline uint pk_bf16(float a, float b) {
    return (uint)f2b(a) | ((uint)f2b(b) << 16);
}
#endif

// 4-way ADDITIVE bias lookup (log2 domain), bf16 table via raw v_perm_b32.
// __builtin_amdgcn_perm selectors are BYTE-packed (b = low source, idx 0-3;
// a = high, 4-7). (__byte_perm is CUDA-prmt NIBBLE-packed — R8's failure.)
__device__ inline void bsel4(uint E, uint tlo, uint thi,
                             float b0, float b1, float b2, float bl[4]) {
#if defined(__HIP_DEVICE_COMPILE__) && __has_builtin(__builtin_amdgcn_perm)
    uint E2  = E + E;                 // per-byte 2e (e<=3: no carry)
    uint E2b = E2 | 0x01010101u;      // per-byte 2e+1
    uint s01 = __builtin_amdgcn_perm(E2b, E2, 0x05010400u);  // [2e0,2e0+1,2e1,2e1+1]
    uint s23 = __builtin_amdgcn_perm(E2b, E2, 0x07030602u);  // [2e2,2e2+1,2e3,2e3+1]
    uint p01 = __builtin_amdgcn_perm(thi, tlo, s01);         // bf16 bl[e0] | bl[e1]<<16
    uint p23 = __builtin_amdgcn_perm(thi, tlo, s23);
    bl[0] = __uint_as_float(p01 << 16);
    bl[1] = __uint_as_float(p01 & 0xFFFF0000u);
    bl[2] = __uint_as_float(p23 << 16);
    bl[3] = __uint_as_float(p23 & 0xFFFF0000u);
#else
    #pragma unroll
    for (int i = 0; i < 4; i++) {
        unsigned char e = (unsigned char)((E >> (8 * i)) & 0xff);
        bl[i] = e == 0 ? b0 : (e == 1 ? b1 : (e == 2 ? b2 : 0.f));
    }
#endif
}

// async global->LDS 16B; fallback if builtin missing (host pass)
__device__ inline void gload16(const ushort* g, ushort* l) {
#if __has_builtin(__builtin_amdgcn_global_load_lds)
    __builtin_amdgcn_global_load_lds(
        (const __attribute__((address_space(1))) void*)g,
        (__attribute__((address_space(3))) void*)l, 16, 0, 0);
#else
    *(short8*)l = *(const short8*)g;
#endif
}

// ---------------------------------------------------------------------------
// build x = [game_token, patch_emb[cell_states]] : (B, S, D) fp32
__global__ __launch_bounds__(256) void build_x(const int* __restrict__ cs,
                                               const float* __restrict__ patch,
                                               const float* __restrict__ game,
                                               float* __restrict__ x)
{
    int idx = blockIdx.x * 256 + threadIdx.x;       // over B*S*D/4 float4s
    int row = idx / (D_ / 4);                        // b*S + s
    int c4  = idx % (D_ / 4);
    int s = row & (S_ - 1);
    float4 v;
    if (s == 0) {
        v = ((const float4*)game)[c4];
    } else {
        int b = row / S_;
        int cell = cs[b * N_ + s - 1];
        v = ((const float4*)(patch + cell * D_))[c4];
    }
    ((float4*)x)[idx] = v;
}

// ---------------------------------------------------------------------------
// et8[b][q][k] = (q>0 && k>0) ? et[b][q-1][k-1] : 3   (3 -> bias 0)
__global__ __launch_bounds__(256) void build_et8(const int* __restrict__ et,
                                                 unsigned char* __restrict__ et8)
{
    long idx = (long)blockIdx.x * 256 + threadIdx.x;  // over B*S*S
    int k = (int)(idx & (S_ - 1));
    long rem = idx >> 9;                              // b*S + q
    int q = (int)(rem & (S_ - 1));
    int b = (int)(rem >> 9);
    unsigned char v = 3;
    if (q > 0 && k > 0) {
        v = (unsigned char)et[((long)b * N_ + (q - 1)) * N_ + (k - 1)];
    }
    et8[idx] = v;
}

// ---------------------------------------------------------------------------
// fp32 -> bf16 weight conversion
__global__ __launch_bounds__(256) void convert_f2b(const float* __restrict__ in,
                                                   ushort* __restrict__ out, int n4)
{
    int i = blockIdx.x * 256 + threadIdx.x;
    if (i >= n4) return;
    float4 v = ((const float4*)in)[i];
    ushort4 o4;
    o4.x = f2b(v.x); o4.y = f2b(v.y); o4.z = f2b(v.z); o4.w = f2b(v.w);
    ((ushort4*)out)[i] = o4;
}

// in_w conversion with Q-rows (row%768 < 256) pre-scaled by QSCL
__global__ __launch_bounds__(256) void convert_inw(const float* __restrict__ in,
                                                   ushort* __restrict__ out)
{
    int i = blockIdx.x * 256 + threadIdx.x;   // over 196608 float4s
    if (i >= 196608) return;
    float4 v = ((const float4*)in)[i];
    int r = (i >> 6) % 768;                   // 64 float4s per 256-col row
    float s = (r < 256) ? (float)QSCL : 1.f;
    ushort4 o4;
    o4.x = f2b(v.x * s); o4.y = f2b(v.y * s); o4.z = f2b(v.z * s); o4.w = f2b(v.w * s);
    ((ushort4*)out)[i] = o4;
}

// ---------------------------------------------------------------------------
// LayerNorm (only for initial x): one wave per row, fp32 in -> bf16 out
__global__ __launch_bounds__(256) void ln_kernel(const float* __restrict__ in,
                                                 ushort* __restrict__ out,
                                                 const float* __restrict__ gw,
                                                 const float* __restrict__ bw)
{
    int t = threadIdx.x;
    int lane = t & 63;
    int r = t >> 6;
    size_t row = (size_t)blockIdx.x * 4 + r;
    float4 v = *(const float4*)(in + row * D_ + lane * 4);
    float s = v.x + v.y + v.z + v.w;
    #pragma unroll
    for (int o = 32; o >= 1; o >>= 1) s += __shfl_xor(s, o);
    float mean = s * (1.f / 256.f);
    float dx = v.x - mean, dy = v.y - mean, dz = v.z - mean, dw = v.w - mean;
    float s2 = dx * dx + dy * dy + dz * dz + dw * dw;
    #pragma unroll
    for (int o = 32; o >= 1; o >>= 1) s2 += __shfl_xor(s2, o);
    float rstd = rsqrtf(s2 * (1.f / 256.f) + 1e-5f);
    float4 g  = *(const float4*)(gw + lane * 4);
    float4 bb = *(const float4*)(bw + lane * 4);
    ushort4 o4;
    o4.x = f2b(dx * rstd * g.x + bb.x);
    o4.y = f2b(dy * rstd * g.y + bb.y);
    o4.z = f2b(dz * rstd * g.z + bb.z);
    o4.w = f2b(dw * rstd * g.w + bb.w);
    *(ushort4*)(out + row * D_ + lane * 4) = o4;
}

// ---------------------------------------------------------------------------
// m97-style LDS GEMM: C = A@W^T + bias, bf16 out (+relu).
// QKV mode: cols 0-255 -> Q into Cout[row*768+col] (QSCL-scaled bias);
//           cols 256-511 -> K into Kb[b,h,s,32]; cols 512-767 -> V^T into
//           Vt[b,h,d,s] (free transpose: lane's 4 r-values = 4 consecutive s).
// 128x128 block tile, BK=32, global_load_lds staging, 4 waves 2x2 of 64x64.
template<int K, int NT, bool RELU, bool QSC, bool QKV>
__global__ __launch_bounds__(256, 2) void gemm_lds(const ushort* __restrict__ A,
                                                   const ushort* __restrict__ W,
                                                   const float* __restrict__ bias,
                                                   ushort* __restrict__ Cout,
                                                   ushort* __restrict__ Kb,
                                                   ushort* __restrict__ Vt)
{
    __shared__ ushort As[4096];    // 128 rows x 32
    __shared__ ushort Ws[4096];
    const int N = NT * 128;
    int t = threadIdx.x;
    int wave = t >> 6, lane = t & 63;
    int lr = lane & 15, quad = lane >> 4;
    int lk = quad * 8;
    int blk = blockIdx.x;                      // grid = NT*256
    int xcd = blk & 7, idx = blk >> 3;
    int m0 = (xcd * 32 + (idx & 31)) * 128;
    int n0 = (idx >> 5) * 128;
    int mh = (wave >> 1) * 64, nh = (wave & 1) * 64;

    const ushort* ga0 = A + (size_t)(m0 + (t >> 2)) * K + (t & 3) * 8;
    const ushort* ga1 = ga0 + (size_t)64 * K;
    const ushort* gw0 = W + (size_t)(n0 + (t >> 2)) * K + (t & 3) * 8;
    const ushort* gw1 = gw0 + (size_t)64 * K;
    ushort* la0 = As + t * 8;
    ushort* la1 = As + t * 8 + 2048;
    ushort* lw0 = Ws + t * 8;
    ushort* lw1 = Ws + t * 8 + 2048;

    f32x4 acc[4][4];
    f32x4 zz = {0.f, 0.f, 0.f, 0.f};
    #pragma unroll
    for (int i = 0; i < 4; i++)
        #pragma unroll
        for (int j = 0; j < 4; j++) acc[i][j] = zz;

    for (int k0 = 0; k0 < K; k0 += 32) {
        gload16(ga0 + k0, la0);
        gload16(ga1 + k0, la1);
        gload16(gw0 + k0, lw0);
        gload16(gw1 + k0, lw1);
        __syncthreads();
        short8 af[4], wf[4];
        #pragma unroll
        for (int i = 0; i < 4; i++) af[i] = *(const short8*)&As[(mh + i * 16 + lr) * 32 + lk];
        #pragma unroll
        for (int j = 0; j < 4; j++) wf[j] = *(const short8*)&Ws[(nh + j * 16 + lr) * 32 + lk];
        #pragma unroll
        for (int i = 0; i < 4; i++)
            #pragma unroll
            for (int j = 0; j < 4; j++)
                acc[i][j] = __builtin_amdgcn_mfma_f32_16x16x32_bf16(af[i], wf[j], acc[i][j], 0, 0, 0);
        __syncthreads();
    }

    #pragma unroll
    for (int nt = 0; nt < 4; nt++) {
        int colbase = n0 + nh + nt * 16;       // 16-aligned; regions 256-aligned
        int col = colbase + lr;
        float bv = bias[col];
        if (QSC && colbase < 256) bv *= (float)QSCL;
        int region = QKV ? (colbase >> 8) : 0; // wave-uniform
        #pragma unroll
        for (int mt = 0; mt < 4; mt++) {
            int rowb = m0 + mh + mt * 16 + quad * 4;
            if (!QKV || region == 0) {
                #pragma unroll
                for (int r = 0; r < 4; r++) {
                    size_t cidx = (size_t)(rowb + r) * N + col;
                    float v = acc[mt][nt][r] + bv;
                    if (RELU) v = fmaxf(v, 0.f);
                    Cout[cidx] = f2b(v);
                }
            } else if (region == 1) {          // K -> Kb[b,h,s,32]
                int hh = (col >> 5) & 7, d = col & 31;
                int bb = rowb >> 9, s = rowb & 511;
                size_t kbase = ((size_t)(bb * 8 + hh) * 512 + s) * 32 + d;
                #pragma unroll
                for (int r = 0; r < 4; r++)
                    Kb[kbase + (size_t)r * 32] = f2b(acc[mt][nt][r] + bv);
            } else {                           // V -> Vt[b,h,d,s] (transposed)
                int hh = (col >> 5) & 7, d = col & 31;
                int bb = rowb >> 9, s = rowb & 511;
                ushort4 w;
                w.x = f2b(acc[mt][nt][0] + bv);
                w.y = f2b(acc[mt][nt][1] + bv);
                w.z = f2b(acc[mt][nt][2] + bv);
                w.w = f2b(acc[mt][nt][3] + bv);
                *(ushort4*)&Vt[((size_t)(bb * 8 + hh) * 32 + d) * 512 + s] = w;
            }
        }
    }
}

// ---------------------------------------------------------------------------
// Fused residual GEMM + LayerNorm: block = 64 rows x 256 cols (full D row).
// x_new = A@W^T + bias + x  (stored fp32); h = LN(x_new)*g+b (stored bf16).
// 4 waves, wave tile 64x64 (1x4 col split); cross-wave row stats via LDS.
template<int K>
__global__ __launch_bounds__(256, 2) void gemm_ln(const ushort* __restrict__ A,
                                                  const ushort* __restrict__ W,
                                                  const float* __restrict__ bias,
                                                  float* __restrict__ X,
                                                  const float* __restrict__ lng,
                                                  const float* __restrict__ lnb,
                                                  ushort* __restrict__ Hout)
{
    __shared__ ushort As[64 * 32];      //  4 KB
    __shared__ ushort Ws[256 * 32];     // 16 KB
    __shared__ float lds_s[64][4];      //  1 KB
    __shared__ float lds_q[64][4];      //  1 KB
    int t = threadIdx.x;
    int wave = t >> 6, lane = t & 63;
    int lr = lane & 15, quad = lane >> 4;
    int lk = quad * 8;
    int blk = blockIdx.x;               // grid 512
    int xcd = blk & 7;
    int m0 = (xcd * 64 + (blk >> 3)) * 64;
    int nh = wave * 64;

    const ushort* ga = A + (size_t)(m0 + (t >> 2)) * K + (t & 3) * 8;
    const ushort* gw = W + (size_t)(t >> 2) * K + (t & 3) * 8;
    ushort* la = As + t * 8;
    ushort* lw = Ws + t * 8;

    f32x4 acc[4][4];
    f32x4 zz = {0.f, 0.f, 0.f, 0.f};
    #pragma unroll
    for (int i = 0; i < 4; i++)
        #pragma unroll
        for (int j = 0; j < 4; j++) acc[i][j] = zz;

    for (int k0 = 0; k0 < K; k0 += 32) {
        gload16(ga + k0, la);
        #pragma unroll
        for (int j = 0; j < 4; j++)
            gload16(gw + (size_t)(j * 64) * K + k0, lw + j * 2048);
        __syncthreads();
        short8 af[4], wf[4];
        #pragma unroll
        for (int i = 0; i < 4; i++) af[i] = *(const short8*)&As[(i * 16 + lr) * 32 + lk];
        #pragma unroll
        for (int j = 0; j < 4; j++) wf[j] = *(const short8*)&Ws[(nh + j * 16 + lr) * 32 + lk];
        #pragma unroll
        for (int i = 0; i < 4; i++)
            #pragma unroll
            for (int j = 0; j < 4; j++)
                acc[i][j] = __builtin_amdgcn_mfma_f32_16x16x32_bf16(af[i], wf[j], acc[i][j], 0, 0, 0);
        __syncthreads();
    }

    // epilogue pass 1: v = acc + bias + X; store X; keep v in acc; row partials
    float gc[4], bc[4], bi[4];
    #pragma unroll
    for (int nt = 0; nt < 4; nt++) {
        int col = nh + nt * 16 + lr;
        gc[nt] = lng[col]; bc[nt] = lnb[col]; bi[nt] = bias[col];
    }
    float psum[16], psq[16];
    #pragma unroll
    for (int e = 0; e < 16; e++) { psum[e] = 0.f; psq[e] = 0.f; }
    #pragma unroll
    for (int nt = 0; nt < 4; nt++) {
        #pragma unroll
        for (int mt = 0; mt < 4; mt++) {
            #pragma unroll
            for (int r = 0; r < 4; r++) {
                int row = m0 + mt * 16 + quad * 4 + r;
                size_t idx = (size_t)row * D_ + nh + nt * 16 + lr;
                float v = acc[mt][nt][r] + bi[nt] + X[idx];
                X[idx] = v;
                acc[mt][nt][r] = v;
                psum[mt * 4 + r] += v;
                psq[mt * 4 + r]  += v * v;
            }
        }
    }
    // reduce over lr (16 lanes per quad hold disjoint cols of same rows)
    #pragma unroll
    for (int e = 0; e < 16; e++) {
        float s = psum[e], q = psq[e];
        s += __shfl_xor(s, 1); q += __shfl_xor(q, 1);
        s += __shfl_xor(s, 2); q += __shfl_xor(q, 2);
        s += __shfl_xor(s, 4); q += __shfl_xor(q, 4);
        s += __shfl_xor(s, 8); q += __shfl_xor(q, 8);
        psum[e] = s; psq[e] = q;
    }
    if (lr == 0) {
        #pragma unroll
        for (int mt = 0; mt < 4; mt++)
            #pragma unroll
            for (int r = 0; r < 4; r++) {
                int rl = mt * 16 + quad * 4 + r;
                lds_s[rl][wave] = psum[mt * 4 + r];
                lds_q[rl][wave] = psq[mt * 4 + r];
            }
    }
    __syncthreads();
    // epilogue pass 2: finalize stats, write h
    #pragma unroll
    for (int mt = 0; mt < 4; mt++) {
        #pragma unroll
        for (int r = 0; r < 4; r++) {
            int rl = mt * 16 + quad * 4 + r;
            f32x4 ss = *(const f32x4*)lds_s[rl];
            f32x4 qq = *(const f32x4*)lds_q[rl];
            float s = ss[0] + ss[1] + ss[2] + ss[3];
            float q = qq[0] + qq[1] + qq[2] + qq[3];
            float mean = s * (1.f / 256.f);
            float rstd = rsqrtf(q * (1.f / 256.f) - mean * mean + 1e-5f);
            int row = m0 + mt * 16 + quad * 4 + r;
            #pragma unroll
            for (int nt = 0; nt < 4; nt++) {
                size_t idx = (size_t)row * D_ + nh + nt * 16 + lr;
                float hv = (acc[mt][nt][r] - mean) * rstd * gc[nt] + bc[nt];
                Hout[idx] = f2b(hv);
            }
        }
    }
}

// ---------------------------------------------------------------------------
// Flash attention, SPLIT-K. Block = 4 waves = 2 q-groups x 2 k-halves.
// Each wave: 64 q rows (4 x 16 tiles, R10 ILP preserved) over 256 keys.
// no-max softmax makes cross-k combine exact: add raw oacc+lsum via LDS.
// Grid 2048 -> 8 waves/SIMD (R10 was wave-starved at 4; R11 proved TLP must
// not cost ILP regs: (256,8) on 2-tile kernel squeezed VGPR 56->32, regressed).
__global__ __launch_bounds__(256, 8) void attn_mfma(const ushort* __restrict__ qkv,
                                                    const ushort* __restrict__ Kb,
                                                    const ushort* __restrict__ Vt,
                                                    const unsigned char* __restrict__ et8,
                                                    const float* __restrict__ eemb,
                                                    ushort* __restrict__ o)
{
    __shared__ float comb[2][64][37];        // [qg][lane][32 oacc + 4 lsum], 37 coprime 32
    int t = threadIdx.x;
    int wave = t >> 6, lane = t & 63;
    int lr = lane & 15, quad = lane >> 4;
    int lk = quad * 8;
    int blk = blockIdx.x;                    // grid 2048
    int b = ((blk >> 8) << 3) | (blk & 7);   // same-b blocks -> same XCD
    int rest = (blk >> 3) & 31;
    int h = rest & 7;
    int qblk = rest >> 3;                    // 0..3 (128-q block)
    int bh = b * 8 + h;
    int qg = wave & 1, kh = wave >> 1;       // q-group, k-half
    int q0 = qblk * 128 + qg * 64;
    int kbeg = kh * 256;
    // additive bias table (log2 domain): exp2(s + b*L2E)
    float eb0 = eemb[h] * L2E, eb1 = eemb[8 + h] * L2E, eb2 = eemb[16 + h] * L2E;
    uint tlo = (uint)f2b(eb0) | ((uint)f2b(eb1) << 16);
    uint thi = (uint)f2b(eb2);               // high half = bf16 0.0 for e==3

    short8 qf[4];
    #pragma unroll
    for (int X = 0; X < 4; X++)
        qf[X] = *(const short8*)(qkv + ((size_t)(b * S_ + q0 + X * 16 + lr)) * 768 + h * 32 + lk);
    const ushort* Kp = Kb + ((size_t)(bh * S_ + lr)) * 32 + lk;
    const unsigned char* Ep = et8 + ((size_t)(b * S_ + q0 + lr)) * S_ + quad * 4;
    const ushort* Vp0 = Vt + ((size_t)(bh * 32) + lr) * S_ + quad * 4;       // d 0..15
    const ushort* Vp1 = Vp0 + (size_t)16 * S_;                               // d 16..31

    f32x4 zz = {0.f, 0.f, 0.f, 0.f};
    f32x4 oacc[4][2];
    float lsum[4];
    #pragma unroll
    for (int X = 0; X < 4; X++) { oacc[X][0] = zz; oacc[X][1] = zz; lsum[X] = 0.f; }

    short8 kf0 = *(const short8*)(Kp + (size_t)kbeg * 32);
    short8 kf1 = *(const short8*)(Kp + (size_t)(kbeg + 16) * 32);

    for (int k0 = kbeg; k0 < kbeg + 256; k0 += 32) {
        int kn = (k0 + 32) & (S_ - 1);           // wrap anywhere in S: harmless
        short8 nk0 = *(const short8*)(Kp + (size_t)kn * 32);
        short8 nk1 = *(const short8*)(Kp + (size_t)(kn + 16) * 32);
        short4v vf00 = *(const short4v*)(Vp0 + k0);
        short4v vf01 = *(const short4v*)(Vp1 + k0);
        short4v vf10 = *(const short4v*)(Vp0 + k0 + 16);
        short4v vf11 = *(const short4v*)(Vp1 + k0 + 16);
        uint Earr[8];
        #pragma unroll
        for (int X = 0; X < 4; X++) {
            Earr[2 * X]     = *(const uint*)(Ep + (size_t)X * 16 * S_ + k0);
            Earr[2 * X + 1] = *(const uint*)(Ep + (size_t)X * 16 * S_ + k0 + 16);
        }
        #pragma unroll
        for (int X = 0; X < 4; X++) {
            // S^T: lane holds S[q=lr][k = k0 + (0|16) + quad*4 + r]
            f32x4 s0 = __builtin_amdgcn_mfma_f32_16x16x32_bf16(kf0, qf[X], zz, 0, 0, 0);
            f32x4 s1 = __builtin_amdgcn_mfma_f32_16x16x32_bf16(kf1, qf[X], zz, 0, 0, 0);
            float bl0[4], bl1[4];
            bsel4(Earr[2 * X],     tlo, thi, eb0, eb1, eb2, bl0);
            bsel4(Earr[2 * X + 1], tlo, thi, eb0, eb1, eb2, bl1);
            float p0[4], p1[4];
            #pragma unroll
            for (int r = 0; r < 4; r++) {
                p0[r] = EXP2(s0[r] + bl0[r]);
                p1[r] = EXP2(s1[r] + bl1[r]);
                lsum[X] += p0[r] + p1[r];
            }
            union { short4v v; uint2 u; } P0, P1;
            P0.u.x = pk_bf16(p0[0], p0[1]); P0.u.y = pk_bf16(p0[2], p0[3]);
            P1.u.x = pk_bf16(p1[0], p1[1]); P1.u.y = pk_bf16(p1[2], p1[3]);
            // P already in 16x16x16 A-layout: lane holds P[q=lr][k=quad*4+j]
            oacc[X][0] = MFMA16(P0.v, vf00, oacc[X][0]);
            oacc[X][1] = MFMA16(P0.v, vf01, oacc[X][1]);
            oacc[X][0] = MFMA16(P1.v, vf10, oacc[X][0]);
            oacc[X][1] = MFMA16(P1.v, vf11, oacc[X][1]);
        }
        kf0 = nk0; kf1 = nk1;
    }

    // ---- combine k-halves (exact: raw partial sums add) ----
    if (kh == 1) {
        float* c = comb[qg][lane];
        #pragma unroll
        for (int X = 0; X < 4; X++) {
            #pragma unroll
            for (int r = 0; r < 4; r++) {
                c[X * 8 + r]     = oacc[X][0][r];
                c[X * 8 + 4 + r] = oacc[X][1][r];
            }
        }
        #pragma unroll
        for (int X = 0; X < 4; X++) c[32 + X] = lsum[X];
    }
    __syncthreads();
    if (kh == 1) return;

    {
        const float* c = comb[qg][lane];
        #pragma unroll
        for (int X = 0; X < 4; X++) {
            #pragma unroll
            for (int r = 0; r < 4; r++) {
                oacc[X][0][r] += c[X * 8 + r];
                oacc[X][1][r] += c[X * 8 + 4 + r];
            }
            lsum[X] += c[32 + X];
        }
    }

    #pragma unroll
    for (int X = 0; X < 4; X++) {
        float ls = lsum[X];
        ls += __shfl_xor(ls, 16);
        ls += __shfl_xor(ls, 32);
        #pragma unroll
        for (int r = 0; r < 4; r++) {
            int q = quad * 4 + r;                 // O rows: q, cols d = lr
            float inv = 1.f / __shfl(ls, q);      // sum for row q lives at lane q
            size_t base = (size_t)(b * S_ + q0 + X * 16 + q) * D_ + h * 32;
            o[base + lr]      = f2b(oacc[X][0][r] * inv);
            o[base + 16 + lr] = f2b(oacc[X][1][r] * inv);
        }
    }
}

// ---------------------------------------------------------------------------
// Head (fp32)
__global__ __launch_bounds__(64) void head_kernel(const float* __restrict__ x,
                                                  const float* __restrict__ fc1w,
                                                  const float* __restrict__ fc1b,
                                                  const float* __restrict__ polw,
                                                  const float* __restrict__ polb,
                                                  const float* __restrict__ valw,
                                                  const float* __restrict__ valb,
                                                  float* __restrict__ out)
{
    __shared__ float o1[64];
    int b = blockIdx.x;
    int t = threadIdx.x;
    const float* g = x + (size_t)b * S_ * D_;
    float acc = fc1b[t];
    for (int k = 0; k < D_; k++) acc += g[k] * fc1w[t * D_ + k];
    o1[t] = fmaxf(acc, 0.f);
    __syncthreads();
    if (t < BW_) {
        float a = polb[t];
        for (int k = 0; k < 64; k++) a += o1[k] * polw[t * 64 + k];
        out[b * BW_ + t] = a;
    } else if (t == BW_) {
        float a = valb[0];
        for (int k = 0; k < 64; k++) a += o1[k] * valw[k];
        out[B_ * BW_ + b] = tanhf(a);
    }
}

// ---------------------------------------------------------------------------
extern "C" void kernel_launch(void* const* d_in, const int* in_sizes, int n_in,
                              void* d_out, int out_size, void* d_ws, size_t ws_size,
                              hipStream_t stream)
{
    const int*   cs    = (const int*)d_in[0];
    const int*   etm   = (const int*)d_in[1];
    const float* patch = (const float*)d_in[2];
    const float* game  = (const float*)d_in[3];
    const float* eemb  = (const float*)d_in[4];
    const float* in_w  = (const float*)d_in[5];
    const float* in_b  = (const float*)d_in[6];
    const float* out_w = (const float*)d_in[7];
    const float* out_b = (const float*)d_in[8];
    const float* ff1_w = (const float*)d_in[9];
    const float* ff1_b = (const float*)d_in[10];
    const float* ff2_w = (const float*)d_in[11];
    const float* ff2_b = (const float*)d_in[12];
    const float* ln1_g = (const float*)d_in[13];
    const float* ln1_b = (const float*)d_in[14];
    const float* ln2_g = (const float*)d_in[15];
    const float* ln2_b = (const float*)d_in[16];
    const float* fc1_w = (const float*)d_in[17];
    const float* fc1_b = (const float*)d_in[18];
    const float* pol_w = (const float*)d_in[19];
    const float* pol_b = (const float*)d_in[20];
    const float* val_w = (const float*)d_in[21];
    const float* val_b = (const float*)d_in[22];
    float* out = (float*)d_out;

    char* base = (char*)d_ws;
    float*  x     = (float*)(base + 0);                    // 33554432 B
    ushort* h     = (ushort*)(base + 33554432);            // 16777216 B
    ushort* qkvb  = (ushort*)(base + 50331648);            // 50331648 B (also FF buf)
    ushort* Kb    = (ushort*)(base + 100663296);           // 16777216 B
    ushort* Vt    = (ushort*)(base + 117440512);           // 16777216 B
    ushort* ob    = (ushort*)(base + 134217728);           // 16777216 B
    unsigned char* et8 = (unsigned char*)(base + 150994944); // 16777216 B
    ushort* inwb  = (ushort*)(base + 167772160);           //  1572864 B
    ushort* outwb = (ushort*)(base + 169345024);           //   524288 B
    ushort* ff1wb = (ushort*)(base + 169869312);           //  1048576 B
    ushort* ff2wb = (ushort*)(base + 170917888);           //  1048576 B

    build_x<<<8192, 256, 0, stream>>>(cs, patch, game, x);
    build_et8<<<65536, 256, 0, stream>>>(etm, et8);
    convert_inw<<<768, 256, 0, stream>>>(in_w, inwb);
    convert_f2b<<<256, 256, 0, stream>>>(out_w, outwb, 65536);
    convert_f2b<<<512, 256, 0, stream>>>(ff1_w, ff1wb, 131072);
    convert_f2b<<<512, 256, 0, stream>>>(ff2_w, ff2wb, 131072);

    // initial LN1 (layer 0); subsequent LNs are fused into gemm_ln epilogues
    ln_kernel<<<8192, 256, 0, stream>>>(x, h, ln1_g, ln1_b);

    for (int i = 0; i < L_; i++) {
        // qkv GEMM with fused K/V repack (Q -> qkvb, K -> Kb, V^T -> Vt)
        gemm_lds<256, 6, false, true, true><<<1536, 256, 0, stream>>>(
            h, inwb + (size_t)i * 196608, in_b + i * 768, qkvb, Kb, Vt);
        attn_mfma<<<2048, 256, 0, stream>>>(qkvb, Kb, Vt, et8, eemb, ob);
        // out-proj + residual + LN2 -> x (fp32), h (bf16)
        gemm_ln<256><<<512, 256, 0, stream>>>(
            ob, outwb + (size_t)i * 65536, out_b + i * 256, x,
            ln2_g + i * D_, ln2_b + i * D_, h);
        gemm_lds<256, 4, true, false, false><<<1024, 256, 0, stream>>>(
            h, ff1wb + (size_t)i * 131072, ff1_b + i * 512, qkvb, nullptr, nullptr);
        // ff2 + residual + LN1(next layer) -> x (fp32), h (bf16)
        int nx = (i + 1 < L_) ? (i + 1) : i;   // last layer: h unused
        gemm_ln<512><<<512, 256, 0, stream>>>(
            qkvb, ff2wb + (size_t)i * 131072, ff2_b + i * 256, x,
            ln1_g + nx * D_, ln1_b + nx * D_, h);
    }
    head_kernel<<<B_, 64, 0, stream>>>(x, fc1_w, fc1_b, pol_w, pol_b, val_w, val_b, out);
}

// Round 14
// 802.261 us; speedup vs baseline: 2.3517x; 2.3517x over previous
//
#include <hip/hip_runtime.h>
#include <hip/hip_bf16.h>
#include <math.h>

#define L_ 4
#define B_ 64
#define N_ 511
#define D_ 256
#define H_ 8
#define DFF_ 512
#define S_ 512
#define HD_ 32
#define BW_ 7
#define BS_ (B_*S_)   // 32768 rows

typedef __attribute__((ext_vector_type(8))) short short8;   // 8 x bf16 bits
typedef __attribute__((ext_vector_type(4))) short short4v;  // 4 x bf16 bits
typedef __attribute__((ext_vector_type(4))) float f32x4;

#define L2E 1.44269504088896340f
#define QSCL (0.17677669529663687f * 1.44269504088896340f)   // rscale * log2(e)

// Device pass: resolve the 16x16x16 bf16 MFMA spelling. Host pass: stub.
#if defined(__HIP_DEVICE_COMPILE__)
#if __has_builtin(__builtin_amdgcn_mfma_f32_16x16x16bf16_1k)
#define MFMA16(p, v, c) __builtin_amdgcn_mfma_f32_16x16x16bf16_1k(p, v, c, 0, 0, 0)
#elif __has_builtin(__builtin_amdgcn_mfma_f32_16x16x16_bf16)
#define MFMA16(p, v, c) __builtin_amdgcn_mfma_f32_16x16x16_bf16(p, v, c, 0, 0, 0)
#else
#define MFMA16(p, v, c) (c)   /* unreachable on gfx950 per R4 evidence */
#endif
#else
#define MFMA16(p, v, c) (c)   /* host pass: never executed */
#endif

#if defined(__HIP_DEVICE_COMPILE__) && __has_builtin(__builtin_amdgcn_exp2f)
#define EXP2(x) __builtin_amdgcn_exp2f(x)
#else
#define EXP2(x) exp2f(x)
#endif

__device__ inline ushort f2b(float f) {
    unsigned u = __float_as_uint(f);
    unsigned r = (u + 0x7fffu + ((u >> 16) & 1u)) >> 16;   // RNE
    return (ushort)r;
}

// packed f32x2 -> bf16x2 in one uint (low = a); HW op on gfx950, SW fallback
#if defined(__HIP_DEVICE_COMPILE__) && __has_builtin(__builtin_amdgcn_cvt_pk_bf16_f32)
typedef __attribute__((ext_vector_type(2))) __bf16 bf16x2_t;
__device__ inline uint pk_bf16(float a, float b) {
    bf16x2_t r = __builtin_amdgcn_cvt_pk_bf16_f32(a, b);
    return *(uint*)&r;
}
#else
__device__ inline uint pk_bf16(float a, float b) {
    return (uint)f2b(a) | ((uint)f2b(b) << 16);
}
#endif

// 4-way ADDITIVE bias lookup (log2 domain), bf16 table via raw v_perm_b32.
// __builtin_amdgcn_perm selectors are BYTE-packed (b = low source, idx 0-3;
// a = high, 4-7). (__byte_perm is CUDA-prmt NIBBLE-packed — R8's failure.)
__device__ inline void bsel4(uint E, uint tlo, uint thi,
                             float b0, float b1, float b2, float bl[4]) {
#if defined(__HIP_DEVICE_COMPILE__) && __has_builtin(__builtin_amdgcn_perm)
    uint E2  = E + E;                 // per-byte 2e (e<=3: no carry)
    uint E2b = E2 | 0x01010101u;      // per-byte 2e+1
    uint s01 = __builtin_amdgcn_perm(E2b, E2, 0x05010400u);  // [2e0,2e0+1,2e1,2e1+1]
    uint s23 = __builtin_amdgcn_perm(E2b, E2, 0x07030602u);  // [2e2,2e2+1,2e3,2e3+1]
    uint p01 = __builtin_amdgcn_perm(thi, tlo, s01);         // bf16 bl[e0] | bl[e1]<<16
    uint p23 = __builtin_amdgcn_perm(thi, tlo, s23);
    bl[0] = __uint_as_float(p01 << 16);
    bl[1] = __uint_as_float(p01 & 0xFFFF0000u);
    bl[2] = __uint_as_float(p23 << 16);
    bl[3] = __uint_as_float(p23 & 0xFFFF0000u);
#else
    #pragma unroll
    for (int i = 0; i < 4; i++) {
        unsigned char e = (unsigned char)((E >> (8 * i)) & 0xff);
        bl[i] = e == 0 ? b0 : (e == 1 ? b1 : (e == 2 ? b2 : 0.f));
    }
#endif
}

// async global->LDS 16B; fallback if builtin missing (host pass)
__device__ inline void gload16(const void* g, void* l) {
#if __has_builtin(__builtin_amdgcn_global_load_lds)
    __builtin_amdgcn_global_load_lds(
        (const __attribute__((address_space(1))) void*)g,
        (__attribute__((address_space(3))) void*)l, 16, 0, 0);
#else
    *(short8*)l = *(const short8*)g;
#endif
}

// ---------------------------------------------------------------------------
// build x = [game_token, patch_emb[cell_states]] : (B, S, D) fp32
__global__ __launch_bounds__(256) void build_x(const int* __restrict__ cs,
                                               const float* __restrict__ patch,
                                               const float* __restrict__ game,
                                               float* __restrict__ x)
{
    int idx = blockIdx.x * 256 + threadIdx.x;       // over B*S*D/4 float4s
    int row = idx / (D_ / 4);                        // b*S + s
    int c4  = idx % (D_ / 4);
    int s = row & (S_ - 1);
    float4 v;
    if (s == 0) {
        v = ((const float4*)game)[c4];
    } else {
        int b = row / S_;
        int cell = cs[b * N_ + s - 1];
        v = ((const float4*)(patch + cell * D_))[c4];
    }
    ((float4*)x)[idx] = v;
}

// ---------------------------------------------------------------------------
// et8[b][q][k] = (q>0 && k>0) ? et[b][q-1][k-1] : 3   (3 -> bias 0)
__global__ __launch_bounds__(256) void build_et8(const int* __restrict__ et,
                                                 unsigned char* __restrict__ et8)
{
    long idx = (long)blockIdx.x * 256 + threadIdx.x;  // over B*S*S
    int k = (int)(idx & (S_ - 1));
    long rem = idx >> 9;                              // b*S + q
    int q = (int)(rem & (S_ - 1));
    int b = (int)(rem >> 9);
    unsigned char v = 3;
    if (q > 0 && k > 0) {
        v = (unsigned char)et[((long)b * N_ + (q - 1)) * N_ + (k - 1)];
    }
    et8[idx] = v;
}

// ---------------------------------------------------------------------------
// fp32 -> bf16 weight conversion
__global__ __launch_bounds__(256) void convert_f2b(const float* __restrict__ in,
                                                   ushort* __restrict__ out, int n4)
{
    int i = blockIdx.x * 256 + threadIdx.x;
    if (i >= n4) return;
    float4 v = ((const float4*)in)[i];
    ushort4 o4;
    o4.x = f2b(v.x); o4.y = f2b(v.y); o4.z = f2b(v.z); o4.w = f2b(v.w);
    ((ushort4*)out)[i] = o4;
}

// in_w conversion with Q-rows (row%768 < 256) pre-scaled by QSCL
__global__ __launch_bounds__(256) void convert_inw(const float* __restrict__ in,
                                                   ushort* __restrict__ out)
{
    int i = blockIdx.x * 256 + threadIdx.x;   // over 196608 float4s
    if (i >= 196608) return;
    float4 v = ((const float4*)in)[i];
    int r = (i >> 6) % 768;                   // 64 float4s per 256-col row
    float s = (r < 256) ? (float)QSCL : 1.f;
    ushort4 o4;
    o4.x = f2b(v.x * s); o4.y = f2b(v.y * s); o4.z = f2b(v.z * s); o4.w = f2b(v.w * s);
    ((ushort4*)out)[i] = o4;
}

// ---------------------------------------------------------------------------
// LayerNorm (only for initial x): one wave per row, fp32 in -> bf16 out
__global__ __launch_bounds__(256) void ln_kernel(const float* __restrict__ in,
                                                 ushort* __restrict__ out,
                                                 const float* __restrict__ gw,
                                                 const float* __restrict__ bw)
{
    int t = threadIdx.x;
    int lane = t & 63;
    int r = t >> 6;
    size_t row = (size_t)blockIdx.x * 4 + r;
    float4 v = *(const float4*)(in + row * D_ + lane * 4);
    float s = v.x + v.y + v.z + v.w;
    #pragma unroll
    for (int o = 32; o >= 1; o >>= 1) s += __shfl_xor(s, o);
    float mean = s * (1.f / 256.f);
    float dx = v.x - mean, dy = v.y - mean, dz = v.z - mean, dw = v.w - mean;
    float s2 = dx * dx + dy * dy + dz * dz + dw * dw;
    #pragma unroll
    for (int o = 32; o >= 1; o >>= 1) s2 += __shfl_xor(s2, o);
    float rstd = rsqrtf(s2 * (1.f / 256.f) + 1e-5f);
    float4 g  = *(const float4*)(gw + lane * 4);
    float4 bb = *(const float4*)(bw + lane * 4);
    ushort4 o4;
    o4.x = f2b(dx * rstd * g.x + bb.x);
    o4.y = f2b(dy * rstd * g.y + bb.y);
    o4.z = f2b(dz * rstd * g.z + bb.z);
    o4.w = f2b(dw * rstd * g.w + bb.w);
    *(ushort4*)(out + row * D_ + lane * 4) = o4;
}

// ---------------------------------------------------------------------------
// m97-style LDS GEMM: C = A@W^T + bias, bf16 out (+relu).
// QKV mode: cols 0-255 -> Q into Cout[row*768+col] (QSCL-scaled bias);
//           cols 256-511 -> K into Kb[b,h,s,32]; cols 512-767 -> V^T into
//           TILED Vt[bh][s/16][d][16] (1KB-contiguous per 16-k tile so
//           attention V fragment loads hit adjacent lines, not 16 KB scatter).
// 128x128 block tile, BK=32, global_load_lds staging, 4 waves 2x2 of 64x64.
template<int K, int NT, bool RELU, bool QSC, bool QKV>
__global__ __launch_bounds__(256, 2) void gemm_lds(const ushort* __restrict__ A,
                                                   const ushort* __restrict__ W,
                                                   const float* __restrict__ bias,
                                                   ushort* __restrict__ Cout,
                                                   ushort* __restrict__ Kb,
                                                   ushort* __restrict__ Vt)
{
    __shared__ ushort As[4096];    // 128 rows x 32
    __shared__ ushort Ws[4096];
    const int N = NT * 128;
    int t = threadIdx.x;
    int wave = t >> 6, lane = t & 63;
    int lr = lane & 15, quad = lane >> 4;
    int lk = quad * 8;
    int blk = blockIdx.x;                      // grid = NT*256
    int xcd = blk & 7, idx = blk >> 3;
    int m0 = (xcd * 32 + (idx & 31)) * 128;
    int n0 = (idx >> 5) * 128;
    int mh = (wave >> 1) * 64, nh = (wave & 1) * 64;

    const ushort* ga0 = A + (size_t)(m0 + (t >> 2)) * K + (t & 3) * 8;
    const ushort* ga1 = ga0 + (size_t)64 * K;
    const ushort* gw0 = W + (size_t)(n0 + (t >> 2)) * K + (t & 3) * 8;
    const ushort* gw1 = gw0 + (size_t)64 * K;
    ushort* la0 = As + t * 8;
    ushort* la1 = As + t * 8 + 2048;
    ushort* lw0 = Ws + t * 8;
    ushort* lw1 = Ws + t * 8 + 2048;

    f32x4 acc[4][4];
    f32x4 zz = {0.f, 0.f, 0.f, 0.f};
    #pragma unroll
    for (int i = 0; i < 4; i++)
        #pragma unroll
        for (int j = 0; j < 4; j++) acc[i][j] = zz;

    for (int k0 = 0; k0 < K; k0 += 32) {
        gload16(ga0 + k0, la0);
        gload16(ga1 + k0, la1);
        gload16(gw0 + k0, lw0);
        gload16(gw1 + k0, lw1);
        __syncthreads();
        short8 af[4], wf[4];
        #pragma unroll
        for (int i = 0; i < 4; i++) af[i] = *(const short8*)&As[(mh + i * 16 + lr) * 32 + lk];
        #pragma unroll
        for (int j = 0; j < 4; j++) wf[j] = *(const short8*)&Ws[(nh + j * 16 + lr) * 32 + lk];
        #pragma unroll
        for (int i = 0; i < 4; i++)
            #pragma unroll
            for (int j = 0; j < 4; j++)
                acc[i][j] = __builtin_amdgcn_mfma_f32_16x16x32_bf16(af[i], wf[j], acc[i][j], 0, 0, 0);
        __syncthreads();
    }

    #pragma unroll
    for (int nt = 0; nt < 4; nt++) {
        int colbase = n0 + nh + nt * 16;       // 16-aligned; regions 256-aligned
        int col = colbase + lr;
        float bv = bias[col];
        if (QSC && colbase < 256) bv *= (float)QSCL;
        int region = QKV ? (colbase >> 8) : 0; // wave-uniform
        #pragma unroll
        for (int mt = 0; mt < 4; mt++) {
            int rowb = m0 + mh + mt * 16 + quad * 4;
            if (!QKV || region == 0) {
                #pragma unroll
                for (int r = 0; r < 4; r++) {
                    size_t cidx = (size_t)(rowb + r) * N + col;
                    float v = acc[mt][nt][r] + bv;
                    if (RELU) v = fmaxf(v, 0.f);
                    Cout[cidx] = f2b(v);
                }
            } else if (region == 1) {          // K -> Kb[b,h,s,32]
                int hh = (col >> 5) & 7, d = col & 31;
                int bb = rowb >> 9, s = rowb & 511;
                size_t kbase = ((size_t)(bb * 8 + hh) * 512 + s) * 32 + d;
                #pragma unroll
                for (int r = 0; r < 4; r++)
                    Kb[kbase + (size_t)r * 32] = f2b(acc[mt][nt][r] + bv);
            } else {                           // V -> Vt[bh][s/16][d][16] tiled
                int hh = (col >> 5) & 7, d = col & 31;
                int bb = rowb >> 9, s = rowb & 511;
                ushort4 w;
                w.x = f2b(acc[mt][nt][0] + bv);
                w.y = f2b(acc[mt][nt][1] + bv);
                w.z = f2b(acc[mt][nt][2] + bv);
                w.w = f2b(acc[mt][nt][3] + bv);
                size_t vidx = (((size_t)(bb * 8 + hh) * 32 + (s >> 4)) * 32 + d) * 16 + (s & 15);
                *(ushort4*)&Vt[vidx] = w;
            }
        }
    }
}

// ---------------------------------------------------------------------------
// Fused residual GEMM + LayerNorm: block = 64 rows x 256 cols (full D row).
// x_new = A@W^T + bias + x  (stored fp32); h = LN(x_new)*g+b (stored bf16).
// 4 waves, wave tile 64x64 (1x4 col split); cross-wave row stats via LDS.
template<int K>
__global__ __launch_bounds__(256, 2) void gemm_ln(const ushort* __restrict__ A,
                                                  const ushort* __restrict__ W,
                                                  const float* __restrict__ bias,
                                                  float* __restrict__ X,
                                                  const float* __restrict__ lng,
                                                  const float* __restrict__ lnb,
                                                  ushort* __restrict__ Hout)
{
    __shared__ ushort As[64 * 32];      //  4 KB
    __shared__ ushort Ws[256 * 32];     // 16 KB
    __shared__ float lds_s[64][4];      //  1 KB
    __shared__ float lds_q[64][4];      //  1 KB
    int t = threadIdx.x;
    int wave = t >> 6, lane = t & 63;
    int lr = lane & 15, quad = lane >> 4;
    int lk = quad * 8;
    int blk = blockIdx.x;               // grid 512
    int xcd = blk & 7;
    int m0 = (xcd * 64 + (blk >> 3)) * 64;
    int nh = wave * 64;

    const ushort* ga = A + (size_t)(m0 + (t >> 2)) * K + (t & 3) * 8;
    const ushort* gw = W + (size_t)(t >> 2) * K + (t & 3) * 8;
    ushort* la = As + t * 8;
    ushort* lw = Ws + t * 8;

    f32x4 acc[4][4];
    f32x4 zz = {0.f, 0.f, 0.f, 0.f};
    #pragma unroll
    for (int i = 0; i < 4; i++)
        #pragma unroll
        for (int j = 0; j < 4; j++) acc[i][j] = zz;

    for (int k0 = 0; k0 < K; k0 += 32) {
        gload16(ga + k0, la);
        #pragma unroll
        for (int j = 0; j < 4; j++)
            gload16(gw + (size_t)(j * 64) * K + k0, lw + j * 2048);
        __syncthreads();
        short8 af[4], wf[4];
        #pragma unroll
        for (int i = 0; i < 4; i++) af[i] = *(const short8*)&As[(i * 16 + lr) * 32 + lk];
        #pragma unroll
        for (int j = 0; j < 4; j++) wf[j] = *(const short8*)&Ws[(nh + j * 16 + lr) * 32 + lk];
        #pragma unroll
        for (int i = 0; i < 4; i++)
            #pragma unroll
            for (int j = 0; j < 4; j++)
                acc[i][j] = __builtin_amdgcn_mfma_f32_16x16x32_bf16(af[i], wf[j], acc[i][j], 0, 0, 0);
        __syncthreads();
    }

    // epilogue pass 1: v = acc + bias + X; store X; keep v in acc; row partials
    float gc[4], bc[4], bi[4];
    #pragma unroll
    for (int nt = 0; nt < 4; nt++) {
        int col = nh + nt * 16 + lr;
        gc[nt] = lng[col]; bc[nt] = lnb[col]; bi[nt] = bias[col];
    }
    float psum[16], psq[16];
    #pragma unroll
    for (int e = 0; e < 16; e++) { psum[e] = 0.f; psq[e] = 0.f; }
    #pragma unroll
    for (int nt = 0; nt < 4; nt++) {
        #pragma unroll
        for (int mt = 0; mt < 4; mt++) {
            #pragma unroll
            for (int r = 0; r < 4; r++) {
                int row = m0 + mt * 16 + quad * 4 + r;
                size_t idx = (size_t)row * D_ + nh + nt * 16 + lr;
                float v = acc[mt][nt][r] + bi[nt] + X[idx];
                X[idx] = v;
                acc[mt][nt][r] = v;
                psum[mt * 4 + r] += v;
                psq[mt * 4 + r]  += v * v;
            }
        }
    }
    // reduce over lr (16 lanes per quad hold disjoint cols of same rows)
    #pragma unroll
    for (int e = 0; e < 16; e++) {
        float s = psum[e], q = psq[e];
        s += __shfl_xor(s, 1); q += __shfl_xor(q, 1);
        s += __shfl_xor(s, 2); q += __shfl_xor(q, 2);
        s += __shfl_xor(s, 4); q += __shfl_xor(q, 4);
        s += __shfl_xor(s, 8); q += __shfl_xor(q, 8);
        psum[e] = s; psq[e] = q;
    }
    if (lr == 0) {
        #pragma unroll
        for (int mt = 0; mt < 4; mt++)
            #pragma unroll
            for (int r = 0; r < 4; r++) {
                int rl = mt * 16 + quad * 4 + r;
                lds_s[rl][wave] = psum[mt * 4 + r];
                lds_q[rl][wave] = psq[mt * 4 + r];
            }
    }
    __syncthreads();
    // epilogue pass 2: finalize stats, write h
    #pragma unroll
    for (int mt = 0; mt < 4; mt++) {
        #pragma unroll
        for (int r = 0; r < 4; r++) {
            int rl = mt * 16 + quad * 4 + r;
            f32x4 ss = *(const f32x4*)lds_s[rl];
            f32x4 qq = *(const f32x4*)lds_q[rl];
            float s = ss[0] + ss[1] + ss[2] + ss[3];
            float q = qq[0] + qq[1] + qq[2] + qq[3];
            float mean = s * (1.f / 256.f);
            float rstd = rsqrtf(q * (1.f / 256.f) - mean * mean + 1e-5f);
            int row = m0 + mt * 16 + quad * 4 + r;
            #pragma unroll
            for (int nt = 0; nt < 4; nt++) {
                size_t idx = (size_t)row * D_ + nh + nt * 16 + lr;
                float hv = (acc[mt][nt][r] - mean) * rstd * gc[nt] + bc[nt];
                Hout[idx] = f2b(hv);
            }
        }
    }
}

// ---------------------------------------------------------------------------
// Flash attention (R10 structure + gather fixes; R13's staging offsets FIXED).
// block = (b,h,256 q) = 4 waves x 64 q; X=4 ILP chains; launch_bounds(256,4).
// Est geometry: Est[buf][half][4096 B] -> buf stride 8192 B, half stride 4096 B.
// (R13 used 16384/8192 — buf1 writes landed OUT OF BOUNDS -> garbage bias.)
__global__ __launch_bounds__(256, 4) void attn_mfma(const ushort* __restrict__ qkv,
                                                    const ushort* __restrict__ Kb,
                                                    const ushort* __restrict__ Vt,
                                                    const unsigned char* __restrict__ et8,
                                                    const float* __restrict__ eemb,
                                                    ushort* __restrict__ o)
{
    __shared__ unsigned char Est[2][2][4096];   // [buf][lo/hi][256 q][16 k] = 16 KB
    int t = threadIdx.x;
    int wave = t >> 6, lane = t & 63;
    int lr = lane & 15, quad = lane >> 4;
    int lk = quad * 8;
    int blk = blockIdx.x;                    // grid 1024
    int b = ((blk >> 7) << 3) | (blk & 7);   // same-b blocks -> same XCD
    int rest = (blk >> 3) & 15;
    int h = rest & 7;
    int qhalf = rest >> 3;
    int bh = b * 8 + h;
    int q0 = qhalf * 256 + wave * 64;
    // additive bias table (log2 domain): exp2(s + b*L2E)
    float eb0 = eemb[h] * L2E, eb1 = eemb[8 + h] * L2E, eb2 = eemb[16 + h] * L2E;
    uint tlo = (uint)f2b(eb0) | ((uint)f2b(eb1) << 16);
    uint thi = (uint)f2b(eb2);               // high half = bf16 0.0 for e==3

    short8 qf[4];
    #pragma unroll
    for (int X = 0; X < 4; X++)
        qf[X] = *(const short8*)(qkv + ((size_t)(b * S_ + q0 + X * 16 + lr)) * 768 + h * 32 + lk);
    const ushort* Kp = Kb + ((size_t)(bh * S_ + lr)) * 32 + lk;
    // tiled V: element [s16][d][sl]; lane base at d=lr, sl=quad*4
    const ushort* Vp = Vt + (size_t)bh * 32 * 512 + lr * 16 + quad * 4;
    // E staging: thread t owns q-row (qhalf*256 + t); lane-linear dest (i*16)
    const unsigned char* Ep = et8 + ((size_t)(b * S_ + qhalf * 256 + t)) * S_;
    unsigned char* ElD = &Est[0][0][t * 16];

    f32x4 zz = {0.f, 0.f, 0.f, 0.f};
    f32x4 oacc[4][2];
    float lsum[4];
    #pragma unroll
    for (int X = 0; X < 4; X++) { oacc[X][0] = zz; oacc[X][1] = zz; lsum[X] = 0.f; }

    // prime: stage E for k0=0 into buf 0 (halves at +0 / +4096)
    gload16(Ep + 0,  ElD);
    gload16(Ep + 16, ElD + 4096);
    short8 kf0 = *(const short8*)(Kp);
    short8 kf1 = *(const short8*)(Kp + 16 * 32);
    __syncthreads();

    for (int k0 = 0; k0 < S_; k0 += 32) {
        int cb = (k0 >> 5) & 1, nb = cb ^ 1;
        if (k0 < S_ - 32) {
            gload16(Ep + k0 + 32, ElD + (size_t)nb * 8192);
            gload16(Ep + k0 + 48, ElD + (size_t)nb * 8192 + 4096);
        }
        int kn = (k0 + 32) & (S_ - 1);           // wraps on last iter (harmless)
        short8 nk0 = *(const short8*)(Kp + (size_t)kn * 32);
        short8 nk1 = *(const short8*)(Kp + (size_t)(kn + 16) * 32);
        // V fragments from tiled layout: tiles k0>>4 and (k0>>4)+1
        const ushort* vt0 = Vp + (size_t)(k0 >> 4) * 512;
        short4v vf00 = *(const short4v*)(vt0);            // d 0..15,  k0..k0+15
        short4v vf01 = *(const short4v*)(vt0 + 256);      // d 16..31
        short4v vf10 = *(const short4v*)(vt0 + 512);      // k0+16..+31
        short4v vf11 = *(const short4v*)(vt0 + 768);
        #pragma unroll
        for (int X = 0; X < 4; X++) {
            // S^T: lane holds S[q=lr][k = k0 + (0|16) + quad*4 + r]
            f32x4 s0 = __builtin_amdgcn_mfma_f32_16x16x32_bf16(kf0, qf[X], zz, 0, 0, 0);
            f32x4 s1 = __builtin_amdgcn_mfma_f32_16x16x32_bf16(kf1, qf[X], zz, 0, 0, 0);
            int qrow = wave * 64 + X * 16 + lr;
            uint E0 = *(const uint*)&Est[cb][0][qrow * 16 + quad * 4];
            uint E1 = *(const uint*)&Est[cb][1][qrow * 16 + quad * 4];
            float bl0[4], bl1[4];
            bsel4(E0, tlo, thi, eb0, eb1, eb2, bl0);
            bsel4(E1, tlo, thi, eb0, eb1, eb2, bl1);
            float p0[4], p1[4];
            #pragma unroll
            for (int r = 0; r < 4; r++) {
                p0[r] = EXP2(s0[r] + bl0[r]);
                p1[r] = EXP2(s1[r] + bl1[r]);
                lsum[X] += p0[r] + p1[r];
            }
            union { short4v v; uint2 u; } P0, P1;
            P0.u.x = pk_bf16(p0[0], p0[1]); P0.u.y = pk_bf16(p0[2], p0[3]);
            P1.u.x = pk_bf16(p1[0], p1[1]); P1.u.y = pk_bf16(p1[2], p1[3]);
            // P already in 16x16x16 A-layout: lane holds P[q=lr][k=quad*4+j]
            oacc[X][0] = MFMA16(P0.v, vf00, oacc[X][0]);
            oacc[X][1] = MFMA16(P0.v, vf01, oacc[X][1]);
            oacc[X][0] = MFMA16(P1.v, vf10, oacc[X][0]);
            oacc[X][1] = MFMA16(P1.v, vf11, oacc[X][1]);
        }
        kf0 = nk0; kf1 = nk1;
        __syncthreads();   // readers of buf cb done; nb staged (vmcnt drained)
    }

    #pragma unroll
    for (int X = 0; X < 4; X++) {
        float ls = lsum[X];
        ls += __shfl_xor(ls, 16);
        ls += __shfl_xor(ls, 32);
        #pragma unroll
        for (int r = 0; r < 4; r++) {
            int q = quad * 4 + r;                 // O rows: q, cols d = lr
            float inv = 1.f / __shfl(ls, q);      // sum for row q lives at lane q
            size_t base = (size_t)(b * S_ + q0 + X * 16 + q) * D_ + h * 32;
            o[base + lr]      = f2b(oacc[X][0][r] * inv);
            o[base + 16 + lr] = f2b(oacc[X][1][r] * inv);
        }
    }
}

// ---------------------------------------------------------------------------
// Head (fp32)
__global__ __launch_bounds__(64) void head_kernel(const float* __restrict__ x,
                                                  const float* __restrict__ fc1w,
                                                  const float* __restrict__ fc1b,
                                                  const float* __restrict__ polw,
                                                  const float* __restrict__ polb,
                                                  const float* __restrict__ valw,
                                                  const float* __restrict__ valb,
                                                  float* __restrict__ out)
{
    __shared__ float o1[64];
    int b = blockIdx.x;
    int t = threadIdx.x;
    const float* g = x + (size_t)b * S_ * D_;
    float acc = fc1b[t];
    for (int k = 0; k < D_; k++) acc += g[k] * fc1w[t * D_ + k];
    o1[t] = fmaxf(acc, 0.f);
    __syncthreads();
    if (t < BW_) {
        float a = polb[t];
        for (int k = 0; k < 64; k++) a += o1[k] * polw[t * 64 + k];
        out[b * BW_ + t] = a;
    } else if (t == BW_) {
        float a = valb[0];
        for (int k = 0; k < 64; k++) a += o1[k] * valw[k];
        out[B_ * BW_ + b] = tanhf(a);
    }
}

// ---------------------------------------------------------------------------
extern "C" void kernel_launch(void* const* d_in, const int* in_sizes, int n_in,
                              void* d_out, int out_size, void* d_ws, size_t ws_size,
                              hipStream_t stream)
{
    const int*   cs    = (const int*)d_in[0];
    const int*   etm   = (const int*)d_in[1];
    const float* patch = (const float*)d_in[2];
    const float* game  = (const float*)d_in[3];
    const float* eemb  = (const float*)d_in[4];
    const float* in_w  = (const float*)d_in[5];
    const float* in_b  = (const float*)d_in[6];
    const float* out_w = (const float*)d_in[7];
    const float* out_b = (const float*)d_in[8];
    const float* ff1_w = (const float*)d_in[9];
    const float* ff1_b = (const float*)d_in[10];
    const float* ff2_w = (const float*)d_in[11];
    const float* ff2_b = (const float*)d_in[12];
    const float* ln1_g = (const float*)d_in[13];
    const float* ln1_b = (const float*)d_in[14];
    const float* ln2_g = (const float*)d_in[15];
    const float* ln2_b = (const float*)d_in[16];
    const float* fc1_w = (const float*)d_in[17];
    const float* fc1_b = (const float*)d_in[18];
    const float* pol_w = (const float*)d_in[19];
    const float* pol_b = (const float*)d_in[20];
    const float* val_w = (const float*)d_in[21];
    const float* val_b = (const float*)d_in[22];
    float* out = (float*)d_out;

    char* base = (char*)d_ws;
    float*  x     = (float*)(base + 0);                    // 33554432 B
    ushort* h     = (ushort*)(base + 33554432);            // 16777216 B
    ushort* qkvb  = (ushort*)(base + 50331648);            // 50331648 B (also FF buf)
    ushort* Kb    = (ushort*)(base + 100663296);           // 16777216 B
    ushort* Vt    = (ushort*)(base + 117440512);           // 16777216 B
    ushort* ob    = (ushort*)(base + 134217728);           // 16777216 B
    unsigned char* et8 = (unsigned char*)(base + 150994944); // 16777216 B
    ushort* inwb  = (ushort*)(base + 167772160);           //  1572864 B
    ushort* outwb = (ushort*)(base + 169345024);           //   524288 B
    ushort* ff1wb = (ushort*)(base + 169869312);           //  1048576 B
    ushort* ff2wb = (ushort*)(base + 170917888);           //  1048576 B

    build_x<<<8192, 256, 0, stream>>>(cs, patch, game, x);
    build_et8<<<65536, 256, 0, stream>>>(etm, et8);
    convert_inw<<<768, 256, 0, stream>>>(in_w, inwb);
    convert_f2b<<<256, 256, 0, stream>>>(out_w, outwb, 65536);
    convert_f2b<<<512, 256, 0, stream>>>(ff1_w, ff1wb, 131072);
    convert_f2b<<<512, 256, 0, stream>>>(ff2_w, ff2wb, 131072);

    // initial LN1 (layer 0); subsequent LNs are fused into gemm_ln epilogues
    ln_kernel<<<8192, 256, 0, stream>>>(x, h, ln1_g, ln1_b);

    for (int i = 0; i < L_; i++) {
        // qkv GEMM with fused K/V repack (Q -> qkvb, K -> Kb, V^T tiled -> Vt)
        gemm_lds<256, 6, false, true, true><<<1536, 256, 0, stream>>>(
            h, inwb + (size_t)i * 196608, in_b + i * 768, qkvb, Kb, Vt);
        attn_mfma<<<1024, 256, 0, stream>>>(qkvb, Kb, Vt, et8, eemb, ob);
        // out-proj + residual + LN2 -> x (fp32), h (bf16)
        gemm_ln<256><<<512, 256, 0, stream>>>(
            ob, outwb + (size_t)i * 65536, out_b + i * 256, x,
            ln2_g + i * D_, ln2_b + i * D_, h);
        gemm_lds<256, 4, true, false, false><<<1024, 256, 0, stream>>>(
            h, ff1wb + (size_t)i * 131072, ff1_b + i * 512, qkvb, nullptr, nullptr);
        // ff2 + residual + LN1(next layer) -> x (fp32), h (bf16)
        int nx = (i + 1 < L_) ? (i + 1) : i;   // last layer: h unused
        gemm_ln<512><<<512, 256, 0, stream>>>(
            qkvb, ff2wb + (size_t)i * 131072, ff2_b + i * 256, x,
            ln1_g + nx * D_, ln1_b + nx * D_, h);
    }
    head_kernel<<<B_, 64, 0, stream>>>(x, fc1_w, fc1_b, pol_w, pol_b, val_w, val_b, out);
}